// Round 8
// baseline (180.826 us; speedup 1.0000x reference)
//
#include <hip/hip_runtime.h>
#include <hip/hip_bf16.h>
#include <stdint.h>

// B=2, N=2048, DIM=1024, HEADS=8, DIM_HEAD=64, INNER=512
// Round 8: (a) flash v4 — S computed in kk-halves + JIT bv loads to cut peak
// VGPR ~244 -> ~211 (kill suspected scratch spills), better MFMA/VALU
// interleave; (b) 3-stage register pipeline in both LDS-free GEMMs (hide
// cross-XCD L3 latency ~600cyc); (c) gemm_out 32x64 wave tiles -> 2 waves/SIMD.
// Accumulation orders preserved -> absmax must stay exactly 1.831e-4.

#define B_ 2
#define N_ 2048
#define DIM_ 1024
#define DH_ 64
#define INNER_ 512
#define ROWS_ 4096
#define BHSTRIDE 131072    // 2048*64 elems per (b,h) for qf/kf/vf

// q scale 1/8 (=DH^-0.5) * log2(e), folded into wq cast; kernel uses exp2.
#define QSCALE 0.18033688011112042f

typedef __bf16 bf16x8 __attribute__((ext_vector_type(8)));
typedef float floatx4 __attribute__((ext_vector_type(4)));

#if __has_builtin(__builtin_amdgcn_exp2f)
#define EXP2(x) __builtin_amdgcn_exp2f(x)
#else
#define EXP2(x) exp2f(x)
#endif

__device__ __forceinline__ ushort f2bf(float f) {
    union { float f; uint32_t u; } v; v.f = f;
    uint32_t u = v.u;
    u += 0x7fffu + ((u >> 16) & 1u);   // RNE
    return (ushort)(u >> 16);
}
__device__ __forceinline__ uint32_t pkbf(float a, float b) {
    return (uint32_t)f2bf(a) | ((uint32_t)f2bf(b) << 16);
}
// frag-major element offset: lane l of a wave holds M=16*T+(l&15),
// k = 32*kc + 8*(l>>4) + j  (j=0..7). nkc = K/32.
__device__ __forceinline__ size_t frag_off(int m, int k, int nkc) {
    return ((size_t)((m >> 4) * nkc + (k >> 5)) * 64 +
            (size_t)((m & 15) | (((k >> 3) & 3) << 4))) * 8 + (k & 7);
}

// ---------------------------------------------------------------------------
// K1: fused setup. blocks 0..255: partial column stats (seq axis).
// blocks 256..2303: weight cast into frag-major layouts.
__global__ __launch_bounds__(256) void setup_fused(
    const float* __restrict__ x, float* __restrict__ ps, float* __restrict__ pq,
    const float* __restrict__ wq, const float* __restrict__ wkv,
    const float* __restrict__ wo, ushort* __restrict__ wqkv_f,
    ushort* __restrict__ wo_f) {
    __shared__ float tile[32][33];
    int bid = blockIdx.x;
    if (bid < 256) {
        int gd = (bid & 7) * 256 + threadIdx.x;   // b*1024 + c
        int ch = bid >> 3;                        // 0..31
        int b = gd >> 10;
        const float* p = x + (size_t)(b * N_ + ch * 64) * DIM_ + (gd & 1023);
        float s = 0.f, q = 0.f;
#pragma unroll 4
        for (int n = 0; n < 64; ++n) { float v = p[(size_t)n * DIM_]; s += v; q += v * v; }
        ps[ch * 2048 + gd] = s;
        pq[ch * 2048 + gd] = q;
        return;
    }
    int t = bid - 256;
    const float* src; ushort* dst; int C, K, k0, ncol0, nglob0; float scale;
    if (t < 512) {
        int kt = t >> 4, nt = t & 15;
        src = wq; dst = wqkv_f; C = 512; K = 1024; scale = QSCALE;
        k0 = kt * 32; ncol0 = nt * 32; nglob0 = ncol0;
    } else if (t < 1536) {
        int u = t - 512; int kt = u >> 5, nt = u & 31;
        src = wkv; dst = wqkv_f; C = 1024; K = 1024; scale = 1.f;
        k0 = kt * 32; ncol0 = nt * 32; nglob0 = 512 + ncol0;
    } else {
        int u = t - 1536; int kt = u >> 5, nt = u & 31;
        src = wo; dst = wo_f; C = 1024; K = 512; scale = 1.f;
        k0 = kt * 32; ncol0 = nt * 32; nglob0 = ncol0;
    }
    int ti = threadIdx.x >> 5, tj = threadIdx.x & 31;
#pragma unroll
    for (int p = 0; p < 4; ++p)
        tile[ti + 8 * p][tj] = src[(size_t)(k0 + ti + 8 * p) * C + ncol0 + tj] * scale;
    __syncthreads();
    if (threadIdx.x < 128) {
        int nl = threadIdx.x & 31, kc8 = threadIdx.x >> 5;
        union { ushort us[8]; uint4 v; } u;
#pragma unroll
        for (int ii = 0; ii < 8; ++ii) u.us[ii] = f2bf(tile[kc8 * 8 + ii][nl]);
        *(uint4*)&dst[frag_off(nglob0 + nl, k0 + kc8 * 8, K >> 5)] = u.v;
    }
}

// ---------------------------------------------------------------------------
// K2: fused finalize + normalize + cast to frag-major xn. grid 512, block 256.
__global__ __launch_bounds__(256) void finalize_norm(
    const float* __restrict__ ps, const float* __restrict__ pq,
    const float* __restrict__ x, const float* __restrict__ g,
    ushort* __restrict__ xnf) {
    __shared__ float s4[4][64], q4[4][64], aa[64], bb[64];
    int t = threadIdx.x;
    int b = blockIdx.x >> 8, slab = (blockIdx.x >> 4) & 15, nch = blockIdx.x & 15;
    int c0 = slab * 64;
    {
        int c = t & 63, grp = t >> 6;
        float s = 0.f, q = 0.f;
#pragma unroll
        for (int ch = 0; ch < 8; ++ch) {
            int o = (grp * 8 + ch) * 2048 + b * 1024 + c0 + c;
            s += ps[o]; q += pq[o];
        }
        s4[grp][c] = s; q4[grp][c] = q;
    }
    __syncthreads();
    if (t < 64) {
        float s = s4[0][t] + s4[1][t] + s4[2][t] + s4[3][t];
        float q = q4[0][t] + q4[1][t] + q4[2][t] + q4[3][t];
        float mean = s * (1.f / N_);
        float var = q * (1.f / N_) - mean * mean;
        float rstd = rsqrtf(var + 1e-5f);
        float a = rstd * g[c0 + t];
        aa[t] = a; bb[t] = -mean * a;
    }
    __syncthreads();
    int c4 = (t & 15) * 4, ro = t >> 4;
#pragma unroll
    for (int it = 0; it < 8; ++it) {
        int r = nch * 128 + it * 16 + ro;
        int m = b * 2048 + r;
        float4 xv = *(const float4*)&x[(size_t)m * DIM_ + c0 + c4];
        float v0 = xv.x * aa[c4 + 0] + bb[c4 + 0];
        float v1 = xv.y * aa[c4 + 1] + bb[c4 + 1];
        float v2 = xv.z * aa[c4 + 2] + bb[c4 + 2];
        float v3 = xv.w * aa[c4 + 3] + bb[c4 + 3];
        uint2 u; u.x = pkbf(v0, v1); u.y = pkbf(v2, v3);
        *(uint2*)&xnf[frag_off(m, c0 + c4, 32)] = u;
    }
}

// ---------------------------------------------------------------------------
// LDS-free GEMM core, 3-stage register pipeline (lookahead ~2 kc-steps =
// ~620 cyc: covers cross-XCD L3 latency). Accumulation order = kc ascending,
// (mi,ni) inner — identical to prior rounds.
template <int NKC>
__device__ __forceinline__ void gemm_core3(
    const ushort* __restrict__ pA, const ushort* __restrict__ pB,
    floatx4 (&acc)[4][4]) {
    constexpr int TS = NKC * 512;
    bf16x8 a[3][4], b[3][4];
#pragma unroll
    for (int st = 0; st < 2; ++st)
#pragma unroll
        for (int i = 0; i < 4; ++i) {
            a[st][i] = *(const bf16x8*)(pA + (size_t)i * TS + (size_t)st * 512);
            b[st][i] = *(const bf16x8*)(pB + (size_t)i * TS + (size_t)st * 512);
        }
#pragma unroll
    for (int kc = 0; kc < NKC; ++kc) {
        const int cur = kc % 3;
        const int nxt = (kc + 2) % 3;
        if (kc + 2 < NKC) {
#pragma unroll
            for (int i = 0; i < 4; ++i) {
                a[nxt][i] = *(const bf16x8*)(pA + (size_t)i * TS + (size_t)(kc + 2) * 512);
                b[nxt][i] = *(const bf16x8*)(pB + (size_t)i * TS + (size_t)(kc + 2) * 512);
            }
        }
#pragma unroll
        for (int mi = 0; mi < 4; ++mi)
#pragma unroll
            for (int ni = 0; ni < 4; ++ni)
                acc[mi][ni] = __builtin_amdgcn_mfma_f32_16x16x32_bf16(
                    a[cur][mi], b[cur][ni], acc[mi][ni], 0, 0, 0);
    }
}

// 2x4 variant for gemm_out (32-row wave tiles).
template <int NKC>
__device__ __forceinline__ void gemm_core3_24(
    const ushort* __restrict__ pA, const ushort* __restrict__ pB,
    floatx4 (&acc)[2][4]) {
    constexpr int TS = NKC * 512;
    bf16x8 a[3][2], b[3][4];
#pragma unroll
    for (int st = 0; st < 2; ++st) {
#pragma unroll
        for (int i = 0; i < 2; ++i)
            a[st][i] = *(const bf16x8*)(pA + (size_t)i * TS + (size_t)st * 512);
#pragma unroll
        for (int i = 0; i < 4; ++i)
            b[st][i] = *(const bf16x8*)(pB + (size_t)i * TS + (size_t)st * 512);
    }
#pragma unroll
    for (int kc = 0; kc < NKC; ++kc) {
        const int cur = kc % 3;
        const int nxt = (kc + 2) % 3;
        if (kc + 2 < NKC) {
#pragma unroll
            for (int i = 0; i < 2; ++i)
                a[nxt][i] = *(const bf16x8*)(pA + (size_t)i * TS + (size_t)(kc + 2) * 512);
#pragma unroll
            for (int i = 0; i < 4; ++i)
                b[nxt][i] = *(const bf16x8*)(pB + (size_t)i * TS + (size_t)(kc + 2) * 512);
        }
#pragma unroll
        for (int mi = 0; mi < 2; ++mi)
#pragma unroll
            for (int ni = 0; ni < 4; ++ni)
                acc[mi][ni] = __builtin_amdgcn_mfma_f32_16x16x32_bf16(
                    a[cur][mi], b[cur][ni], acc[mi][ni], 0, 0, 0);
    }
}

// K3: qkv GEMM. 1D grid 768, block 128. XCD swizzle (bid&7).
__global__ __launch_bounds__(128, 2) void gemm_qkv(
    const ushort* __restrict__ xnf, const ushort* __restrict__ wf,
    ushort* __restrict__ qf, ushort* __restrict__ kf, ushort* __restrict__ vf) {
    int tx = threadIdx.x, w = tx >> 6, l = tx & 63;
    int lr = l & 15, lq = l >> 4;
    int bid = blockIdx.x;
    int xcd = bid & 7, t = bid >> 3;          // t: 0..95
    int bx = xcd * 8 + (t & 7);               // 0..63
    int by = t >> 3;                          // 0..11
    const ushort* pA = xnf + (size_t)(bx * 4) * 32 * 512 + l * 8;
    const ushort* pB = wf + (size_t)(by * 8 + w * 4) * 32 * 512 + l * 8;
    floatx4 acc[4][4] = {};
    gemm_core3<32>(pA, pB, acc);
    int col0 = by * 128 + w * 64;
    int bb2 = (bx * 64) >> 11;
    if (by < 8) {
        ushort* qkbase = (by < 4) ? qf : kf;
#pragma unroll
        for (int ni = 0; ni < 4; ++ni) {
            int col = col0 + 16 * ni + lr;
            int hh = (col >> 6) & 7, d = col & 63;
            ushort* base = qkbase + (size_t)(bb2 * 8 + hh) * BHSTRIDE
                           + (d >> 5) * 512 + ((d >> 3) & 3) * 128 + (d & 7)
                           + (4 * lq) * 8;
#pragma unroll
            for (int mi = 0; mi < 4; ++mi) {
                size_t o2 = (size_t)((bx * 4 + mi) & 127) * 1024;
#pragma unroll
                for (int reg = 0; reg < 4; ++reg)
                    base[o2 + reg * 8] = f2bf(acc[mi][ni][reg]);
            }
        }
    } else {
#pragma unroll
        for (int ni = 0; ni < 4; ++ni) {
            int cv = col0 - 1024 + 16 * ni + lr;
            int hh = cv >> 6, d = cv & 63;
            ushort* base = vf + (size_t)(bb2 * 8 + hh) * BHSTRIDE
                           + (d >> 4) * 32768 + (d & 15) * 8;
#pragma unroll
            for (int mi = 0; mi < 4; ++mi) {
                int nn = (bx * 64 + 16 * mi + 4 * lq) & 2047;
                uint2 u;
                u.x = pkbf(acc[mi][ni][0], acc[mi][ni][1]);
                u.y = pkbf(acc[mi][ni][2], acc[mi][ni][3]);
                *(uint2*)&base[(nn >> 5) * 512 + ((nn >> 3) & 3) * 128 + (nn & 7)] = u;
            }
        }
    }
}

// K5: out GEMM. 32x64 wave tiles -> 2048 waves (2/SIMD). 1D grid 1024,
// block 128 (2 waves = adjacent n-tiles). XCD swizzle on m-slabs.
__global__ __launch_bounds__(128, 2) void gemm_out(
    const ushort* __restrict__ af, const ushort* __restrict__ wf,
    float* __restrict__ out) {
    int tx = threadIdx.x, w = tx >> 6, l = tx & 63;
    int lr = l & 15, lq = l >> 4;
    int bid = blockIdx.x;
    int xcd = bid & 7, t = bid >> 3;          // t: 0..127
    int mt = xcd * 16 + (t & 15);             // 0..127 (32-row m-tile)
    int nt = (t >> 4) * 2 + w;                // 0..15 (64-col n-tile)
    const ushort* pA = af + (size_t)(mt * 2) * 16 * 512 + l * 8;
    const ushort* pB = wf + (size_t)(nt * 4) * 16 * 512 + l * 8;
    floatx4 acc[2][4] = {};
    gemm_core3_24<16>(pA, pB, acc);
#pragma unroll
    for (int mi = 0; mi < 2; ++mi)
#pragma unroll
        for (int ni = 0; ni < 4; ++ni) {
            int col = nt * 64 + 16 * ni + lr;
#pragma unroll
            for (int reg = 0; reg < 4; ++reg) {
                int row = mt * 32 + 16 * mi + 4 * lq + reg;
                out[(size_t)row * 1024 + col] = acc[mi][ni][reg];
            }
        }
}

// ---------------------------------------------------------------------------
// K4: flash v4, in-block split-merge (as r7) with register-lean inner loop:
// S computed in kk-halves (c2[2][4] = 32 regs, was 64), bv loaded per-s just
// in time, K prefetch after second S-half. Peak live ~211 VGPR (no spills).
// Accumulation orders (lsum kk 0..3; o s=0 then s=1) preserved.
__global__ __launch_bounds__(256, 2) void flash_attn(
    const ushort* __restrict__ qf, const ushort* __restrict__ kf,
    const ushort* __restrict__ vf, ushort* __restrict__ attnf) {
    __shared__ __align__(16) float sArena[4 * 4352];  // P (loop) / O 64x68 (merge)
    __shared__ float sL[4][64];

    const int tx = threadIdx.x;
    const int w = tx >> 6, l = tx & 63;
    const int lr = l & 15, lq = l >> 4;
    const int bid = blockIdx.x;
    const int bh = (bid & 7) * 2 + ((bid >> 3) & 1);
    const int qt = bid >> 4;                 // 0..31 (tile of 64 q rows)

    const ushort* qfb = qf + (size_t)bh * BHSTRIDE + (size_t)(qt * 4) * 1024 + l * 8;
    const ushort* kfb = kf + (size_t)bh * BHSTRIDE + (size_t)w * 32768 + l * 8;
    const ushort* vfb = vf + (size_t)bh * BHSTRIDE + (size_t)w * 8192 + l * 8;
    ushort* sPw = (ushort*)(sArena + w * 4352);

    bf16x8 bq[4][2];
#pragma unroll
    for (int qq = 0; qq < 4; ++qq)
#pragma unroll
        for (int s = 0; s < 2; ++s)
            bq[qq][s] = *(const bf16x8*)(qfb + qq * 1024 + s * 512);

    floatx4 o[4][4] = {};
    float lsum[4] = {0.f, 0.f, 0.f, 0.f};

    bf16x8 ak[8];
#pragma unroll
    for (int kk = 0; kk < 4; ++kk) {
        ak[kk * 2 + 0] = *(const bf16x8*)(kfb + kk * 1024);
        ak[kk * 2 + 1] = *(const bf16x8*)(kfb + kk * 1024 + 512);
    }

    for (int kt = 0; kt < 8; ++kt) {
        // ---- S half 0 (kk = 0,1) ----
        floatx4 c2[2][4] = {};
#pragma unroll
        for (int s = 0; s < 2; ++s)
#pragma unroll
            for (int kk = 0; kk < 2; ++kk)
#pragma unroll
                for (int qq = 0; qq < 4; ++qq)
                    c2[kk][qq] = __builtin_amdgcn_mfma_f32_16x16x32_bf16(
                        ak[kk * 2 + s], bq[qq][s], c2[kk][qq], 0, 0, 0);
        // exp2 + lsum + P store, keys 0..31
#pragma unroll
        for (int kk = 0; kk < 2; ++kk)
#pragma unroll
            for (int qq = 0; qq < 4; ++qq) {
                float e0 = EXP2(c2[kk][qq][0]);
                float e1 = EXP2(c2[kk][qq][1]);
                float e2 = EXP2(c2[kk][qq][2]);
                float e3 = EXP2(c2[kk][qq][3]);
                lsum[qq] += (e0 + e1) + (e2 + e3);
                uint2 u; u.x = pkbf(e0, e1); u.y = pkbf(e2, e3);
                *(uint2*)&sPw[(16 * qq + lr) * 72 + 16 * kk + 4 * lq] = u;
            }

        // ---- S half 1 (kk = 2,3) ----
#pragma unroll
        for (int kk = 0; kk < 2; ++kk)
#pragma unroll
            for (int qq = 0; qq < 4; ++qq) c2[kk][qq] = floatx4{0.f, 0.f, 0.f, 0.f};
#pragma unroll
        for (int s = 0; s < 2; ++s)
#pragma unroll
            for (int kk = 0; kk < 2; ++kk)
#pragma unroll
                for (int qq = 0; qq < 4; ++qq)
                    c2[kk][qq] = __builtin_amdgcn_mfma_f32_16x16x32_bf16(
                        ak[(kk + 2) * 2 + s], bq[qq][s], c2[kk][qq], 0, 0, 0);

        // bv for s=0 (consumed after exp half1 -> ~300 cyc lead)
        bf16x8 bv0[4];
#pragma unroll
        for (int dt = 0; dt < 4; ++dt)
            bv0[dt] = *(const bf16x8*)(vfb + dt * 32768 + (size_t)(kt * 2 + 0) * 512);

        // exp2 + lsum + P store, keys 32..63
#pragma unroll
        for (int kk = 0; kk < 2; ++kk)
#pragma unroll
            for (int qq = 0; qq < 4; ++qq) {
                float e0 = EXP2(c2[kk][qq][0]);
                float e1 = EXP2(c2[kk][qq][1]);
                float e2 = EXP2(c2[kk][qq][2]);
                float e3 = EXP2(c2[kk][qq][3]);
                lsum[qq] += (e0 + e1) + (e2 + e3);
                uint2 u; u.x = pkbf(e0, e1); u.y = pkbf(e2, e3);
                *(uint2*)&sPw[(16 * qq + lr) * 72 + 16 * (kk + 2) + 4 * lq] = u;
            }

        // K prefetch for kt+1 (consumed next iteration)
        if (kt + 1 < 8) {
            const ushort* kp = kfb + (size_t)(kt + 1) * 4096;
#pragma unroll
            for (int kk = 0; kk < 4; ++kk) {
                ak[kk * 2 + 0] = *(const bf16x8*)(kp + kk * 1024);
                ak[kk * 2 + 1] = *(const bf16x8*)(kp + kk * 1024 + 512);
            }
        }

        // ---- PV s=0 (keys 0..31) ----
        {
            bf16x8 ap[4];
#pragma unroll
            for (int mi = 0; mi < 4; ++mi)
                ap[mi] = *(const bf16x8*)&sPw[(16 * mi + lr) * 72 + 8 * lq];
#pragma unroll
            for (int mi = 0; mi < 4; ++mi)
#pragma unroll
                for (int dt = 0; dt < 4; ++dt)
                    o[mi][dt] = __builtin_amdgcn_mfma_f32_16x16x32_bf16(
                        ap[mi], bv0[dt], o[mi][dt], 0, 0, 0);
        }
        // bv for s=1, then PV s=1 (keys 32..63)
        {
            bf16x8 bv1[4];
#pragma unroll
            for (int dt = 0; dt < 4; ++dt)
                bv1[dt] = *(const bf16x8*)(vfb + dt * 32768 + (size_t)(kt * 2 + 1) * 512);
            bf16x8 ap[4];
#pragma unroll
            for (int mi = 0; mi < 4; ++mi)
                ap[mi] = *(const bf16x8*)&sPw[(16 * mi + lr) * 72 + 32 + 8 * lq];
#pragma unroll
            for (int mi = 0; mi < 4; ++mi)
#pragma unroll
                for (int dt = 0; dt < 4; ++dt)
                    o[mi][dt] = __builtin_amdgcn_mfma_f32_16x16x32_bf16(
                        ap[mi], bv1[dt], o[mi][dt], 0, 0, 0);
        }
    }

    // wave-level l reduction across lq (keys partition)
#pragma unroll
    for (int qq = 0; qq < 4; ++qq) {
        lsum[qq] += __shfl_xor(lsum[qq], 16);
        lsum[qq] += __shfl_xor(lsum[qq], 32);
    }

    // write this wave's O (64q x 64d, row stride 68) + l to LDS
    float* Rw = sArena + w * 4352;
#pragma unroll
    for (int mi = 0; mi < 4; ++mi)
#pragma unroll
        for (int dt = 0; dt < 4; ++dt)
#pragma unroll
            for (int reg = 0; reg < 4; ++reg)
                Rw[(16 * mi + 4 * lq + reg) * 68 + 16 * dt + lr] = o[mi][dt][reg];
    if (lq == 0) {
#pragma unroll
        for (int qq = 0; qq < 4; ++qq) sL[w][16 * qq + lr] = lsum[qq];
    }
    __syncthreads();

    // merge: wave w owns local q rows [16w, 16w+16); sum regions 0..3.
    int qloc = 16 * w + (l >> 2);
    int c0 = (l & 3) * 16;
    float4 acc[4];
#pragma unroll
    for (int rg = 0; rg < 4; ++rg) {
        const float* R = sArena + rg * 4352 + qloc * 68 + c0;
#pragma unroll
        for (int c = 0; c < 4; ++c) {
            float4 v = *(const float4*)&R[4 * c];
            if (rg == 0) acc[c] = v;
            else { acc[c].x += v.x; acc[c].y += v.y; acc[c].z += v.z; acc[c].w += v.w; }
        }
    }
    float ltot = sL[0][qloc] + sL[1][qloc] + sL[2][qloc] + sL[3][qloc];
    float inv = 1.f / ltot;
    int m = (bh >> 3) * 2048 + qt * 64 + qloc;
    int kb = (bh & 7) * 64 + c0;
#pragma unroll
    for (int c = 0; c < 4; ++c) {
        uint2 u;
        u.x = pkbf(acc[c].x * inv, acc[c].y * inv);
        u.y = pkbf(acc[c].z * inv, acc[c].w * inv);
        *(uint2*)&attnf[frag_off(m, kb + 4 * c, 16)] = u;
    }
}

// ---------------------------------------------------------------------------
extern "C" void kernel_launch(void* const* d_in, const int* in_sizes, int n_in,
                              void* d_out, int out_size, void* d_ws, size_t ws_size,
                              hipStream_t stream) {
    const float* x   = (const float*)d_in[0];
    const float* g   = (const float*)d_in[1];
    const float* wq  = (const float*)d_in[2];
    const float* wkv = (const float*)d_in[3];
    const float* wo  = (const float*)d_in[4];
    float* out = (float*)d_out;

    char* ws = (char*)d_ws;
    float*  psum   = (float*)(ws + 0);          // 256K
    float*  psqr   = (float*)(ws + 262144);     // 256K
    ushort* xnf    = (ushort*)(ws + 524288);    // 8.39M frag-major K=1024
    ushort* wqkv_f = (ushort*)(ws + 8912896);   // 3.15M frag-major K=1024
    ushort* wo_f   = (ushort*)(ws + 12058624);  // 1.05M frag-major K=512
    ushort* qfb    = (ushort*)(ws + 13107200);  // 4.19M per-bh frag [row][d]
    ushort* kfb    = (ushort*)(ws + 17301504);  // 4.19M per-bh frag [row][d]
    ushort* vfb    = (ushort*)(ws + 21495808);  // 4.19M per-bh frag [d][key]
    ushort* attnf  = (ushort*)(ws + 25690112);  // 4.19M frag-major K=512

    setup_fused<<<2304, 256, 0, stream>>>(x, psum, psqr, wq, wkv, wo, wqkv_f, wo_f);
    finalize_norm<<<512, 256, 0, stream>>>(psum, psqr, x, g, xnf);
    gemm_qkv<<<768, 128, 0, stream>>>(xnf, wqkv_f, qfb, kfb, vfb);
    flash_attn<<<512, 256, 0, stream>>>(qfb, kfb, vfb, attnf);
    gemm_out<<<1024, 128, 0, stream>>>(attnf, wo_f, out);
}

// Round 9
// 147.979 us; speedup vs baseline: 1.2220x; 1.2220x over previous
//
#include <hip/hip_runtime.h>
#include <hip/hip_bf16.h>
#include <stdint.h>

// B=2, N=2048, DIM=1024, HEADS=8, DIM_HEAD=64, INNER=512
// Round 9: controlled REVERT to round-7 (146.7 us known-good). Round 8's
// three simultaneous changes (+34 us) are rolled back; prime suspect was the
// fully-unrolled 3-stage GEMM K-loop (I-cache bloat: 512 MFMA + 256 loads
// straight-line). Re-baselining with zero confounds.
//
// Structure: flash with IN-BLOCK split-merge (4 waves = 4 key-ranges of one
// 64-row q-tile; LDS merge; writes normalized bf16 attnf directly).
// XCD-locality swizzles (bid%8) on flash and both GEMMs. 5 kernels.

#define B_ 2
#define N_ 2048
#define DIM_ 1024
#define DH_ 64
#define INNER_ 512
#define ROWS_ 4096
#define BHSTRIDE 131072    // 2048*64 elems per (b,h) for qf/kf/vf

// q scale 1/8 (=DH^-0.5) * log2(e), folded into wq cast; kernel uses exp2.
#define QSCALE 0.18033688011112042f

typedef __bf16 bf16x8 __attribute__((ext_vector_type(8)));
typedef float floatx4 __attribute__((ext_vector_type(4)));

#if __has_builtin(__builtin_amdgcn_exp2f)
#define EXP2(x) __builtin_amdgcn_exp2f(x)
#else
#define EXP2(x) exp2f(x)
#endif

__device__ __forceinline__ ushort f2bf(float f) {
    union { float f; uint32_t u; } v; v.f = f;
    uint32_t u = v.u;
    u += 0x7fffu + ((u >> 16) & 1u);   // RNE
    return (ushort)(u >> 16);
}
__device__ __forceinline__ uint32_t pkbf(float a, float b) {
    return (uint32_t)f2bf(a) | ((uint32_t)f2bf(b) << 16);
}
// frag-major element offset: lane l of a wave holds M=16*T+(l&15),
// k = 32*kc + 8*(l>>4) + j  (j=0..7). nkc = K/32.
__device__ __forceinline__ size_t frag_off(int m, int k, int nkc) {
    return ((size_t)((m >> 4) * nkc + (k >> 5)) * 64 +
            (size_t)((m & 15) | (((k >> 3) & 3) << 4))) * 8 + (k & 7);
}

// ---------------------------------------------------------------------------
// K1: fused setup. blocks 0..255: partial column stats (seq axis).
// blocks 256..2303: weight cast into frag-major layouts.
__global__ __launch_bounds__(256) void setup_fused(
    const float* __restrict__ x, float* __restrict__ ps, float* __restrict__ pq,
    const float* __restrict__ wq, const float* __restrict__ wkv,
    const float* __restrict__ wo, ushort* __restrict__ wqkv_f,
    ushort* __restrict__ wo_f) {
    __shared__ float tile[32][33];
    int bid = blockIdx.x;
    if (bid < 256) {
        int gd = (bid & 7) * 256 + threadIdx.x;   // b*1024 + c
        int ch = bid >> 3;                        // 0..31
        int b = gd >> 10;
        const float* p = x + (size_t)(b * N_ + ch * 64) * DIM_ + (gd & 1023);
        float s = 0.f, q = 0.f;
#pragma unroll 4
        for (int n = 0; n < 64; ++n) { float v = p[(size_t)n * DIM_]; s += v; q += v * v; }
        ps[ch * 2048 + gd] = s;
        pq[ch * 2048 + gd] = q;
        return;
    }
    int t = bid - 256;
    const float* src; ushort* dst; int C, K, k0, ncol0, nglob0; float scale;
    if (t < 512) {
        int kt = t >> 4, nt = t & 15;
        src = wq; dst = wqkv_f; C = 512; K = 1024; scale = QSCALE;
        k0 = kt * 32; ncol0 = nt * 32; nglob0 = ncol0;
    } else if (t < 1536) {
        int u = t - 512; int kt = u >> 5, nt = u & 31;
        src = wkv; dst = wqkv_f; C = 1024; K = 1024; scale = 1.f;
        k0 = kt * 32; ncol0 = nt * 32; nglob0 = 512 + ncol0;
    } else {
        int u = t - 1536; int kt = u >> 5, nt = u & 31;
        src = wo; dst = wo_f; C = 1024; K = 512; scale = 1.f;
        k0 = kt * 32; ncol0 = nt * 32; nglob0 = ncol0;
    }
    int ti = threadIdx.x >> 5, tj = threadIdx.x & 31;
#pragma unroll
    for (int p = 0; p < 4; ++p)
        tile[ti + 8 * p][tj] = src[(size_t)(k0 + ti + 8 * p) * C + ncol0 + tj] * scale;
    __syncthreads();
    if (threadIdx.x < 128) {
        int nl = threadIdx.x & 31, kc8 = threadIdx.x >> 5;
        union { ushort us[8]; uint4 v; } u;
#pragma unroll
        for (int ii = 0; ii < 8; ++ii) u.us[ii] = f2bf(tile[kc8 * 8 + ii][nl]);
        *(uint4*)&dst[frag_off(nglob0 + nl, k0 + kc8 * 8, K >> 5)] = u.v;
    }
}

// ---------------------------------------------------------------------------
// K2: fused finalize + normalize + cast to frag-major xn. grid 512, block 256.
__global__ __launch_bounds__(256) void finalize_norm(
    const float* __restrict__ ps, const float* __restrict__ pq,
    const float* __restrict__ x, const float* __restrict__ g,
    ushort* __restrict__ xnf) {
    __shared__ float s4[4][64], q4[4][64], aa[64], bb[64];
    int t = threadIdx.x;
    int b = blockIdx.x >> 8, slab = (blockIdx.x >> 4) & 15, nch = blockIdx.x & 15;
    int c0 = slab * 64;
    {
        int c = t & 63, grp = t >> 6;
        float s = 0.f, q = 0.f;
#pragma unroll
        for (int ch = 0; ch < 8; ++ch) {
            int o = (grp * 8 + ch) * 2048 + b * 1024 + c0 + c;
            s += ps[o]; q += pq[o];
        }
        s4[grp][c] = s; q4[grp][c] = q;
    }
    __syncthreads();
    if (t < 64) {
        float s = s4[0][t] + s4[1][t] + s4[2][t] + s4[3][t];
        float q = q4[0][t] + q4[1][t] + q4[2][t] + q4[3][t];
        float mean = s * (1.f / N_);
        float var = q * (1.f / N_) - mean * mean;
        float rstd = rsqrtf(var + 1e-5f);
        float a = rstd * g[c0 + t];
        aa[t] = a; bb[t] = -mean * a;
    }
    __syncthreads();
    int c4 = (t & 15) * 4, ro = t >> 4;
#pragma unroll
    for (int it = 0; it < 8; ++it) {
        int r = nch * 128 + it * 16 + ro;
        int m = b * 2048 + r;
        float4 xv = *(const float4*)&x[(size_t)m * DIM_ + c0 + c4];
        float v0 = xv.x * aa[c4 + 0] + bb[c4 + 0];
        float v1 = xv.y * aa[c4 + 1] + bb[c4 + 1];
        float v2 = xv.z * aa[c4 + 2] + bb[c4 + 2];
        float v3 = xv.w * aa[c4 + 3] + bb[c4 + 3];
        uint2 u; u.x = pkbf(v0, v1); u.y = pkbf(v2, v3);
        *(uint2*)&xnf[frag_off(m, c0 + c4, 32)] = u;
    }
}

// ---------------------------------------------------------------------------
// LDS-free GEMM core: 2-stage register pipeline, ROLLED kc loop (compact
// code; r8's unrolled 3-stage variant regressed — suspected I-cache bloat).
template <int NKC>
__device__ __forceinline__ void gemm_core(
    const ushort* __restrict__ pA, const ushort* __restrict__ pB,
    floatx4 (&acc)[4][4]) {
    constexpr int TS = NKC * 512;
    bf16x8 a0[4], b0[4], a1[4], b1[4];
#pragma unroll
    for (int i = 0; i < 4; ++i) {
        a0[i] = *(const bf16x8*)(pA + (size_t)i * TS);
        b0[i] = *(const bf16x8*)(pB + (size_t)i * TS);
    }
    for (int kc = 0; kc < NKC; kc += 2) {
#pragma unroll
        for (int i = 0; i < 4; ++i) {
            a1[i] = *(const bf16x8*)(pA + (size_t)i * TS + (size_t)(kc + 1) * 512);
            b1[i] = *(const bf16x8*)(pB + (size_t)i * TS + (size_t)(kc + 1) * 512);
        }
#pragma unroll
        for (int mi = 0; mi < 4; ++mi)
#pragma unroll
            for (int ni = 0; ni < 4; ++ni)
                acc[mi][ni] = __builtin_amdgcn_mfma_f32_16x16x32_bf16(
                    a0[mi], b0[ni], acc[mi][ni], 0, 0, 0);
        if (kc + 2 < NKC) {
#pragma unroll
            for (int i = 0; i < 4; ++i) {
                a0[i] = *(const bf16x8*)(pA + (size_t)i * TS + (size_t)(kc + 2) * 512);
                b0[i] = *(const bf16x8*)(pB + (size_t)i * TS + (size_t)(kc + 2) * 512);
            }
        }
#pragma unroll
        for (int mi = 0; mi < 4; ++mi)
#pragma unroll
            for (int ni = 0; ni < 4; ++ni)
                acc[mi][ni] = __builtin_amdgcn_mfma_f32_16x16x32_bf16(
                    a1[mi], b1[ni], acc[mi][ni], 0, 0, 0);
    }
}

// K3: qkv GEMM. 1D grid 768, block 128. XCD swizzle: XCD j owns bx slab
// j*8..j*8+7 (A rows L2-resident per XCD).
__global__ __launch_bounds__(128) void gemm_qkv(
    const ushort* __restrict__ xnf, const ushort* __restrict__ wf,
    ushort* __restrict__ qf, ushort* __restrict__ kf, ushort* __restrict__ vf) {
    int tx = threadIdx.x, w = tx >> 6, l = tx & 63;
    int lr = l & 15, lq = l >> 4;
    int bid = blockIdx.x;
    int xcd = bid & 7, t = bid >> 3;          // t: 0..95
    int bx = xcd * 8 + (t & 7);               // 0..63
    int by = t >> 3;                          // 0..11
    const ushort* pA = xnf + (size_t)(bx * 4) * 32 * 512 + l * 8;
    const ushort* pB = wf + (size_t)(by * 8 + w * 4) * 32 * 512 + l * 8;
    floatx4 acc[4][4] = {};
    gemm_core<32>(pA, pB, acc);
    int col0 = by * 128 + w * 64;
    int bb2 = (bx * 64) >> 11;
    if (by < 8) {
        ushort* qkbase = (by < 4) ? qf : kf;
#pragma unroll
        for (int ni = 0; ni < 4; ++ni) {
            int col = col0 + 16 * ni + lr;
            int hh = (col >> 6) & 7, d = col & 63;
            ushort* base = qkbase + (size_t)(bb2 * 8 + hh) * BHSTRIDE
                           + (d >> 5) * 512 + ((d >> 3) & 3) * 128 + (d & 7)
                           + (4 * lq) * 8;
#pragma unroll
            for (int mi = 0; mi < 4; ++mi) {
                size_t o2 = (size_t)((bx * 4 + mi) & 127) * 1024;
#pragma unroll
                for (int reg = 0; reg < 4; ++reg)
                    base[o2 + reg * 8] = f2bf(acc[mi][ni][reg]);
            }
        }
    } else {
#pragma unroll
        for (int ni = 0; ni < 4; ++ni) {
            int cv = col0 - 1024 + 16 * ni + lr;
            int hh = cv >> 6, d = cv & 63;
            ushort* base = vf + (size_t)(bb2 * 8 + hh) * BHSTRIDE
                           + (d >> 4) * 32768 + (d & 15) * 8;
#pragma unroll
            for (int mi = 0; mi < 4; ++mi) {
                int nn = (bx * 64 + 16 * mi + 4 * lq) & 2047;
                uint2 u;
                u.x = pkbf(acc[mi][ni][0], acc[mi][ni][1]);
                u.y = pkbf(acc[mi][ni][2], acc[mi][ni][3]);
                *(uint2*)&base[(nn >> 5) * 512 + ((nn >> 3) & 3) * 128 + (nn & 7)] = u;
            }
        }
    }
}

// K5: out GEMM. 1D grid 512, block 128, XCD swizzle as above.
__global__ __launch_bounds__(128) void gemm_out(
    const ushort* __restrict__ af, const ushort* __restrict__ wf,
    float* __restrict__ out) {
    int tx = threadIdx.x, w = tx >> 6, l = tx & 63;
    int lr = l & 15, lq = l >> 4;
    int bid = blockIdx.x;
    int xcd = bid & 7, t = bid >> 3;          // t: 0..63
    int bx = xcd * 8 + (t & 7);               // 0..63
    int by = t >> 3;                          // 0..7
    const ushort* pA = af + (size_t)(bx * 4) * 16 * 512 + l * 8;
    const ushort* pB = wf + (size_t)(by * 8 + w * 4) * 16 * 512 + l * 8;
    floatx4 acc[4][4] = {};
    gemm_core<16>(pA, pB, acc);
    int col0 = by * 128 + w * 64;
#pragma unroll
    for (int mi = 0; mi < 4; ++mi)
#pragma unroll
        for (int ni = 0; ni < 4; ++ni) {
            int col = col0 + 16 * ni + lr;
#pragma unroll
            for (int reg = 0; reg < 4; ++reg) {
                int row = bx * 64 + 16 * mi + 4 * lq + reg;
                out[(size_t)row * 1024 + col] = acc[mi][ni][reg];
            }
        }
}

// ---------------------------------------------------------------------------
// K4: flash with in-block split-merge. 1D grid 512 (XCD swizzle: XCD j owns
// bh {2j, 2j+1} -> K/V L2-resident per XCD). Block 256 = 4 waves, each wave
// = SAME 64 q-rows x its own 512-key range (barrier-free inner loop);
// one __syncthreads, LDS merge (sum O, sum l, normalize), write bf16 attnf
// frag-major. Arena regions double as per-wave P buffers during the loop.
__global__ __launch_bounds__(256, 2) void flash_attn(
    const ushort* __restrict__ qf, const ushort* __restrict__ kf,
    const ushort* __restrict__ vf, ushort* __restrict__ attnf) {
    __shared__ __align__(16) float sArena[4 * 4352];  // 4 regions: P (loop) / O 64x68 (merge)
    __shared__ float sL[4][64];

    const int tx = threadIdx.x;
    const int w = tx >> 6, l = tx & 63;
    const int lr = l & 15, lq = l >> 4;
    const int bid = blockIdx.x;
    const int bh = (bid & 7) * 2 + ((bid >> 3) & 1);
    const int qt = bid >> 4;                 // 0..31 (tile of 64 q rows)

    const ushort* qfb = qf + (size_t)bh * BHSTRIDE + (size_t)(qt * 4) * 1024 + l * 8;
    const ushort* kfb = kf + (size_t)bh * BHSTRIDE + (size_t)w * 32768 + l * 8;
    const ushort* vfb = vf + (size_t)bh * BHSTRIDE + (size_t)w * 8192 + l * 8;
    ushort* sPw = (ushort*)(sArena + w * 4352);

    // Q frags (B operand), resident: 4 qq-tiles x 2 k-halves
    bf16x8 bq[4][2];
#pragma unroll
    for (int qq = 0; qq < 4; ++qq)
#pragma unroll
        for (int s = 0; s < 2; ++s)
            bq[qq][s] = *(const bf16x8*)(qfb + qq * 1024 + s * 512);

    floatx4 o[4][4] = {};
    float lsum[4] = {0.f, 0.f, 0.f, 0.f};

    bf16x8 ak[8], bv[8];
#pragma unroll
    for (int kk = 0; kk < 4; ++kk) {
        ak[kk * 2 + 0] = *(const bf16x8*)(kfb + kk * 1024);
        ak[kk * 2 + 1] = *(const bf16x8*)(kfb + kk * 1024 + 512);
    }

    for (int kt = 0; kt < 8; ++kt) {
        // V loads for this kt (consumed at PV, far later)
#pragma unroll
        for (int dt = 0; dt < 4; ++dt) {
            bv[dt * 2 + 0] = *(const bf16x8*)(vfb + dt * 32768 + (kt * 2 + 0) * 512);
            bv[dt * 2 + 1] = *(const bf16x8*)(vfb + dt * 32768 + (kt * 2 + 1) * 512);
        }

        // S^T = K . Q^T : c[kk][qq], rows=keys(16kk+4lq+reg), cols=q(16qq+lr)
        floatx4 c[4][4] = {};
#pragma unroll
        for (int s = 0; s < 2; ++s)
#pragma unroll
            for (int kk = 0; kk < 4; ++kk)
#pragma unroll
                for (int qq = 0; qq < 4; ++qq)
                    c[kk][qq] = __builtin_amdgcn_mfma_f32_16x16x32_bf16(
                        ak[kk * 2 + s], bq[qq][s], c[kk][qq], 0, 0, 0);

        // prefetch K for kt+1
        if (kt + 1 < 8) {
            const ushort* kp = kfb + (size_t)(kt + 1) * 4096;
#pragma unroll
            for (int kk = 0; kk < 4; ++kk) {
                ak[kk * 2 + 0] = *(const bf16x8*)(kp + kk * 1024);
                ak[kk * 2 + 1] = *(const bf16x8*)(kp + kk * 1024 + 512);
            }
        }

        // exp2, row-sums, pack consecutive-key pairs -> per-wave P
#pragma unroll
        for (int kk = 0; kk < 4; ++kk)
#pragma unroll
            for (int qq = 0; qq < 4; ++qq) {
                float e0 = EXP2(c[kk][qq][0]);
                float e1 = EXP2(c[kk][qq][1]);
                float e2 = EXP2(c[kk][qq][2]);
                float e3 = EXP2(c[kk][qq][3]);
                lsum[qq] += (e0 + e1) + (e2 + e3);
                uint2 u; u.x = pkbf(e0, e1); u.y = pkbf(e2, e3);
                *(uint2*)&sPw[(16 * qq + lr) * 72 + 16 * kk + 4 * lq] = u;
            }

        // O += P @ V
#pragma unroll
        for (int s = 0; s < 2; ++s) {
            bf16x8 ap[4];
#pragma unroll
            for (int mi = 0; mi < 4; ++mi)
                ap[mi] = *(const bf16x8*)&sPw[(16 * mi + lr) * 72 + 32 * s + 8 * lq];
#pragma unroll
            for (int mi = 0; mi < 4; ++mi)
#pragma unroll
                for (int dt = 0; dt < 4; ++dt)
                    o[mi][dt] = __builtin_amdgcn_mfma_f32_16x16x32_bf16(
                        ap[mi], bv[dt * 2 + s], o[mi][dt], 0, 0, 0);
        }
    }

    // wave-level l reduction across lq (keys partition)
#pragma unroll
    for (int qq = 0; qq < 4; ++qq) {
        lsum[qq] += __shfl_xor(lsum[qq], 16);
        lsum[qq] += __shfl_xor(lsum[qq], 32);
    }

    // write this wave's O (64q x 64d, row stride 68: <=2-way banks) + l to LDS
    float* Rw = sArena + w * 4352;
#pragma unroll
    for (int mi = 0; mi < 4; ++mi)
#pragma unroll
        for (int dt = 0; dt < 4; ++dt)
#pragma unroll
            for (int reg = 0; reg < 4; ++reg)
                Rw[(16 * mi + 4 * lq + reg) * 68 + 16 * dt + lr] = o[mi][dt][reg];
    if (lq == 0) {
#pragma unroll
        for (int qq = 0; qq < 4; ++qq) sL[w][16 * qq + lr] = lsum[qq];
    }
    __syncthreads();

    // merge: wave w owns local q rows [16w, 16w+16); lane: row 16w+(l>>2),
    // d chunk (l&3)*16. Sum regions 0..3 (same order as old split merge).
    int qloc = 16 * w + (l >> 2);
    int c0 = (l & 3) * 16;
    float4 acc[4];
#pragma unroll
    for (int rg = 0; rg < 4; ++rg) {
        const float* R = sArena + rg * 4352 + qloc * 68 + c0;
#pragma unroll
        for (int c = 0; c < 4; ++c) {
            float4 v = *(const float4*)&R[4 * c];
            if (rg == 0) acc[c] = v;
            else { acc[c].x += v.x; acc[c].y += v.y; acc[c].z += v.z; acc[c].w += v.w; }
        }
    }
    float ltot = sL[0][qloc] + sL[1][qloc] + sL[2][qloc] + sL[3][qloc];
    float inv = 1.f / ltot;
    int m = (bh >> 3) * 2048 + qt * 64 + qloc;
    int kb = (bh & 7) * 64 + c0;
#pragma unroll
    for (int c = 0; c < 4; ++c) {
        uint2 u;
        u.x = pkbf(acc[c].x * inv, acc[c].y * inv);
        u.y = pkbf(acc[c].z * inv, acc[c].w * inv);
        *(uint2*)&attnf[frag_off(m, kb + 4 * c, 16)] = u;
    }
}

// ---------------------------------------------------------------------------
extern "C" void kernel_launch(void* const* d_in, const int* in_sizes, int n_in,
                              void* d_out, int out_size, void* d_ws, size_t ws_size,
                              hipStream_t stream) {
    const float* x   = (const float*)d_in[0];
    const float* g   = (const float*)d_in[1];
    const float* wq  = (const float*)d_in[2];
    const float* wkv = (const float*)d_in[3];
    const float* wo  = (const float*)d_in[4];
    float* out = (float*)d_out;

    char* ws = (char*)d_ws;
    float*  psum   = (float*)(ws + 0);          // 256K
    float*  psqr   = (float*)(ws + 262144);     // 256K
    ushort* xnf    = (ushort*)(ws + 524288);    // 8.39M frag-major K=1024
    ushort* wqkv_f = (ushort*)(ws + 8912896);   // 3.15M frag-major K=1024
    ushort* wo_f   = (ushort*)(ws + 12058624);  // 1.05M frag-major K=512
    ushort* qfb    = (ushort*)(ws + 13107200);  // 4.19M per-bh frag [row][d]
    ushort* kfb    = (ushort*)(ws + 17301504);  // 4.19M per-bh frag [row][d]
    ushort* vfb    = (ushort*)(ws + 21495808);  // 4.19M per-bh frag [d][key]
    ushort* attnf  = (ushort*)(ws + 25690112);  // 4.19M frag-major K=512

    setup_fused<<<2304, 256, 0, stream>>>(x, psum, psqr, wq, wkv, wo, wqkv_f, wo_f);
    finalize_norm<<<512, 256, 0, stream>>>(psum, psqr, x, g, xnf);
    gemm_qkv<<<768, 128, 0, stream>>>(xnf, wqkv_f, qfb, kfb, vfb);
    flash_attn<<<512, 256, 0, stream>>>(qfb, kfb, vfb, attnf);
    gemm_out<<<512, 128, 0, stream>>>(attnf, wo_f, out);
}

// Round 10
// 144.200 us; speedup vs baseline: 1.2540x; 1.0262x over previous
//
#include <hip/hip_runtime.h>
#include <hip/hip_bf16.h>
#include <stdint.h>

// B=2, N=2048, DIM=1024, HEADS=8, DIM_HEAD=64, INNER=512
// Round 10: ONE change vs round 9 — gemm_core 2-stage -> ROLLED 3-stage
// register pipeline (3-buffer rotation, kc+=3). Loads issue 2 MFMA-stages
// (~300-500 cyc) ahead of use, covering L2 latency (~200-225 cyc), without
// r8's full-unroll I-cache explosion. Everything else identical to r9.
// Accumulation order unchanged -> absmax must stay exactly 1.831e-4.

#define B_ 2
#define N_ 2048
#define DIM_ 1024
#define DH_ 64
#define INNER_ 512
#define ROWS_ 4096
#define BHSTRIDE 131072    // 2048*64 elems per (b,h) for qf/kf/vf

// q scale 1/8 (=DH^-0.5) * log2(e), folded into wq cast; kernel uses exp2.
#define QSCALE 0.18033688011112042f

typedef __bf16 bf16x8 __attribute__((ext_vector_type(8)));
typedef float floatx4 __attribute__((ext_vector_type(4)));

#if __has_builtin(__builtin_amdgcn_exp2f)
#define EXP2(x) __builtin_amdgcn_exp2f(x)
#else
#define EXP2(x) exp2f(x)
#endif

__device__ __forceinline__ ushort f2bf(float f) {
    union { float f; uint32_t u; } v; v.f = f;
    uint32_t u = v.u;
    u += 0x7fffu + ((u >> 16) & 1u);   // RNE
    return (ushort)(u >> 16);
}
__device__ __forceinline__ uint32_t pkbf(float a, float b) {
    return (uint32_t)f2bf(a) | ((uint32_t)f2bf(b) << 16);
}
// frag-major element offset: lane l of a wave holds M=16*T+(l&15),
// k = 32*kc + 8*(l>>4) + j  (j=0..7). nkc = K/32.
__device__ __forceinline__ size_t frag_off(int m, int k, int nkc) {
    return ((size_t)((m >> 4) * nkc + (k >> 5)) * 64 +
            (size_t)((m & 15) | (((k >> 3) & 3) << 4))) * 8 + (k & 7);
}

// ---------------------------------------------------------------------------
// K1: fused setup. blocks 0..255: partial column stats (seq axis).
// blocks 256..2303: weight cast into frag-major layouts.
__global__ __launch_bounds__(256) void setup_fused(
    const float* __restrict__ x, float* __restrict__ ps, float* __restrict__ pq,
    const float* __restrict__ wq, const float* __restrict__ wkv,
    const float* __restrict__ wo, ushort* __restrict__ wqkv_f,
    ushort* __restrict__ wo_f) {
    __shared__ float tile[32][33];
    int bid = blockIdx.x;
    if (bid < 256) {
        int gd = (bid & 7) * 256 + threadIdx.x;   // b*1024 + c
        int ch = bid >> 3;                        // 0..31
        int b = gd >> 10;
        const float* p = x + (size_t)(b * N_ + ch * 64) * DIM_ + (gd & 1023);
        float s = 0.f, q = 0.f;
#pragma unroll 4
        for (int n = 0; n < 64; ++n) { float v = p[(size_t)n * DIM_]; s += v; q += v * v; }
        ps[ch * 2048 + gd] = s;
        pq[ch * 2048 + gd] = q;
        return;
    }
    int t = bid - 256;
    const float* src; ushort* dst; int C, K, k0, ncol0, nglob0; float scale;
    if (t < 512) {
        int kt = t >> 4, nt = t & 15;
        src = wq; dst = wqkv_f; C = 512; K = 1024; scale = QSCALE;
        k0 = kt * 32; ncol0 = nt * 32; nglob0 = ncol0;
    } else if (t < 1536) {
        int u = t - 512; int kt = u >> 5, nt = u & 31;
        src = wkv; dst = wqkv_f; C = 1024; K = 1024; scale = 1.f;
        k0 = kt * 32; ncol0 = nt * 32; nglob0 = 512 + ncol0;
    } else {
        int u = t - 1536; int kt = u >> 5, nt = u & 31;
        src = wo; dst = wo_f; C = 1024; K = 512; scale = 1.f;
        k0 = kt * 32; ncol0 = nt * 32; nglob0 = ncol0;
    }
    int ti = threadIdx.x >> 5, tj = threadIdx.x & 31;
#pragma unroll
    for (int p = 0; p < 4; ++p)
        tile[ti + 8 * p][tj] = src[(size_t)(k0 + ti + 8 * p) * C + ncol0 + tj] * scale;
    __syncthreads();
    if (threadIdx.x < 128) {
        int nl = threadIdx.x & 31, kc8 = threadIdx.x >> 5;
        union { ushort us[8]; uint4 v; } u;
#pragma unroll
        for (int ii = 0; ii < 8; ++ii) u.us[ii] = f2bf(tile[kc8 * 8 + ii][nl]);
        *(uint4*)&dst[frag_off(nglob0 + nl, k0 + kc8 * 8, K >> 5)] = u.v;
    }
}

// ---------------------------------------------------------------------------
// K2: fused finalize + normalize + cast to frag-major xn. grid 512, block 256.
__global__ __launch_bounds__(256) void finalize_norm(
    const float* __restrict__ ps, const float* __restrict__ pq,
    const float* __restrict__ x, const float* __restrict__ g,
    ushort* __restrict__ xnf) {
    __shared__ float s4[4][64], q4[4][64], aa[64], bb[64];
    int t = threadIdx.x;
    int b = blockIdx.x >> 8, slab = (blockIdx.x >> 4) & 15, nch = blockIdx.x & 15;
    int c0 = slab * 64;
    {
        int c = t & 63, grp = t >> 6;
        float s = 0.f, q = 0.f;
#pragma unroll
        for (int ch = 0; ch < 8; ++ch) {
            int o = (grp * 8 + ch) * 2048 + b * 1024 + c0 + c;
            s += ps[o]; q += pq[o];
        }
        s4[grp][c] = s; q4[grp][c] = q;
    }
    __syncthreads();
    if (t < 64) {
        float s = s4[0][t] + s4[1][t] + s4[2][t] + s4[3][t];
        float q = q4[0][t] + q4[1][t] + q4[2][t] + q4[3][t];
        float mean = s * (1.f / N_);
        float var = q * (1.f / N_) - mean * mean;
        float rstd = rsqrtf(var + 1e-5f);
        float a = rstd * g[c0 + t];
        aa[t] = a; bb[t] = -mean * a;
    }
    __syncthreads();
    int c4 = (t & 15) * 4, ro = t >> 4;
#pragma unroll
    for (int it = 0; it < 8; ++it) {
        int r = nch * 128 + it * 16 + ro;
        int m = b * 2048 + r;
        float4 xv = *(const float4*)&x[(size_t)m * DIM_ + c0 + c4];
        float v0 = xv.x * aa[c4 + 0] + bb[c4 + 0];
        float v1 = xv.y * aa[c4 + 1] + bb[c4 + 1];
        float v2 = xv.z * aa[c4 + 2] + bb[c4 + 2];
        float v3 = xv.w * aa[c4 + 3] + bb[c4 + 3];
        uint2 u; u.x = pkbf(v0, v1); u.y = pkbf(v2, v3);
        *(uint2*)&xnf[frag_off(m, c0 + c4, 32)] = u;
    }
}

// ---------------------------------------------------------------------------
// LDS-free GEMM core: ROLLED 3-stage register pipeline. 3 explicit buffer
// sets rotate through a kc+=3 loop; load of stage kc+2 issues before the
// MFMA block of stage kc (2-stage = ~300-500 cyc lookahead). Compact body
// (48 MFMA + 24 loads), no dynamic indexing, no full unroll.
template <int NKC>
__device__ __forceinline__ void gemm_core(
    const ushort* __restrict__ pA, const ushort* __restrict__ pB,
    floatx4 (&acc)[4][4]) {
    constexpr int TS = NKC * 512;
    bf16x8 a0[4], b0[4], a1[4], b1[4], a2[4], b2[4];
    auto ld = [&](bf16x8 (&a)[4], bf16x8 (&b)[4], int kc) {
#pragma unroll
        for (int i = 0; i < 4; ++i) {
            a[i] = *(const bf16x8*)(pA + (size_t)i * TS + (size_t)kc * 512);
            b[i] = *(const bf16x8*)(pB + (size_t)i * TS + (size_t)kc * 512);
        }
    };
    auto mm = [&](bf16x8 (&a)[4], bf16x8 (&b)[4]) {
#pragma unroll
        for (int mi = 0; mi < 4; ++mi)
#pragma unroll
            for (int ni = 0; ni < 4; ++ni)
                acc[mi][ni] = __builtin_amdgcn_mfma_f32_16x16x32_bf16(
                    a[mi], b[ni], acc[mi][ni], 0, 0, 0);
    };
    ld(a0, b0, 0);
    ld(a1, b1, 1);
    int kc = 0;
    for (; kc + 3 <= NKC; kc += 3) {
        ld(a2, b2, kc + 2);
        mm(a0, b0);
        if (kc + 3 < NKC) ld(a0, b0, kc + 3);
        mm(a1, b1);
        if (kc + 4 < NKC) ld(a1, b1, kc + 4);
        mm(a2, b2);
    }
    if (NKC % 3 >= 1) mm(a0, b0);     // stage kc
    if (NKC % 3 == 2) mm(a1, b1);     // stage kc+1
}

// K3: qkv GEMM. 1D grid 768, block 128. XCD swizzle: XCD j owns bx slab
// j*8..j*8+7 (A rows L2-resident per XCD).
__global__ __launch_bounds__(128) void gemm_qkv(
    const ushort* __restrict__ xnf, const ushort* __restrict__ wf,
    ushort* __restrict__ qf, ushort* __restrict__ kf, ushort* __restrict__ vf) {
    int tx = threadIdx.x, w = tx >> 6, l = tx & 63;
    int lr = l & 15, lq = l >> 4;
    int bid = blockIdx.x;
    int xcd = bid & 7, t = bid >> 3;          // t: 0..95
    int bx = xcd * 8 + (t & 7);               // 0..63
    int by = t >> 3;                          // 0..11
    const ushort* pA = xnf + (size_t)(bx * 4) * 32 * 512 + l * 8;
    const ushort* pB = wf + (size_t)(by * 8 + w * 4) * 32 * 512 + l * 8;
    floatx4 acc[4][4] = {};
    gemm_core<32>(pA, pB, acc);
    int col0 = by * 128 + w * 64;
    int bb2 = (bx * 64) >> 11;
    if (by < 8) {
        ushort* qkbase = (by < 4) ? qf : kf;
#pragma unroll
        for (int ni = 0; ni < 4; ++ni) {
            int col = col0 + 16 * ni + lr;
            int hh = (col >> 6) & 7, d = col & 63;
            ushort* base = qkbase + (size_t)(bb2 * 8 + hh) * BHSTRIDE
                           + (d >> 5) * 512 + ((d >> 3) & 3) * 128 + (d & 7)
                           + (4 * lq) * 8;
#pragma unroll
            for (int mi = 0; mi < 4; ++mi) {
                size_t o2 = (size_t)((bx * 4 + mi) & 127) * 1024;
#pragma unroll
                for (int reg = 0; reg < 4; ++reg)
                    base[o2 + reg * 8] = f2bf(acc[mi][ni][reg]);
            }
        }
    } else {
#pragma unroll
        for (int ni = 0; ni < 4; ++ni) {
            int cv = col0 - 1024 + 16 * ni + lr;
            int hh = cv >> 6, d = cv & 63;
            ushort* base = vf + (size_t)(bb2 * 8 + hh) * BHSTRIDE
                           + (d >> 4) * 32768 + (d & 15) * 8;
#pragma unroll
            for (int mi = 0; mi < 4; ++mi) {
                int nn = (bx * 64 + 16 * mi + 4 * lq) & 2047;
                uint2 u;
                u.x = pkbf(acc[mi][ni][0], acc[mi][ni][1]);
                u.y = pkbf(acc[mi][ni][2], acc[mi][ni][3]);
                *(uint2*)&base[(nn >> 5) * 512 + ((nn >> 3) & 3) * 128 + (nn & 7)] = u;
            }
        }
    }
}

// K5: out GEMM. 1D grid 512, block 128, XCD swizzle as above.
__global__ __launch_bounds__(128) void gemm_out(
    const ushort* __restrict__ af, const ushort* __restrict__ wf,
    float* __restrict__ out) {
    int tx = threadIdx.x, w = tx >> 6, l = tx & 63;
    int lr = l & 15, lq = l >> 4;
    int bid = blockIdx.x;
    int xcd = bid & 7, t = bid >> 3;          // t: 0..63
    int bx = xcd * 8 + (t & 7);               // 0..63
    int by = t >> 3;                          // 0..7
    const ushort* pA = af + (size_t)(bx * 4) * 16 * 512 + l * 8;
    const ushort* pB = wf + (size_t)(by * 8 + w * 4) * 16 * 512 + l * 8;
    floatx4 acc[4][4] = {};
    gemm_core<16>(pA, pB, acc);
    int col0 = by * 128 + w * 64;
#pragma unroll
    for (int mi = 0; mi < 4; ++mi)
#pragma unroll
        for (int ni = 0; ni < 4; ++ni) {
            int col = col0 + 16 * ni + lr;
#pragma unroll
            for (int reg = 0; reg < 4; ++reg) {
                int row = bx * 64 + 16 * mi + 4 * lq + reg;
                out[(size_t)row * 1024 + col] = acc[mi][ni][reg];
            }
        }
}

// ---------------------------------------------------------------------------
// K4: flash with in-block split-merge (byte-identical to round 9).
__global__ __launch_bounds__(256, 2) void flash_attn(
    const ushort* __restrict__ qf, const ushort* __restrict__ kf,
    const ushort* __restrict__ vf, ushort* __restrict__ attnf) {
    __shared__ __align__(16) float sArena[4 * 4352];  // P (loop) / O 64x68 (merge)
    __shared__ float sL[4][64];

    const int tx = threadIdx.x;
    const int w = tx >> 6, l = tx & 63;
    const int lr = l & 15, lq = l >> 4;
    const int bid = blockIdx.x;
    const int bh = (bid & 7) * 2 + ((bid >> 3) & 1);
    const int qt = bid >> 4;                 // 0..31 (tile of 64 q rows)

    const ushort* qfb = qf + (size_t)bh * BHSTRIDE + (size_t)(qt * 4) * 1024 + l * 8;
    const ushort* kfb = kf + (size_t)bh * BHSTRIDE + (size_t)w * 32768 + l * 8;
    const ushort* vfb = vf + (size_t)bh * BHSTRIDE + (size_t)w * 8192 + l * 8;
    ushort* sPw = (ushort*)(sArena + w * 4352);

    bf16x8 bq[4][2];
#pragma unroll
    for (int qq = 0; qq < 4; ++qq)
#pragma unroll
        for (int s = 0; s < 2; ++s)
            bq[qq][s] = *(const bf16x8*)(qfb + qq * 1024 + s * 512);

    floatx4 o[4][4] = {};
    float lsum[4] = {0.f, 0.f, 0.f, 0.f};

    bf16x8 ak[8], bv[8];
#pragma unroll
    for (int kk = 0; kk < 4; ++kk) {
        ak[kk * 2 + 0] = *(const bf16x8*)(kfb + kk * 1024);
        ak[kk * 2 + 1] = *(const bf16x8*)(kfb + kk * 1024 + 512);
    }

    for (int kt = 0; kt < 8; ++kt) {
#pragma unroll
        for (int dt = 0; dt < 4; ++dt) {
            bv[dt * 2 + 0] = *(const bf16x8*)(vfb + dt * 32768 + (kt * 2 + 0) * 512);
            bv[dt * 2 + 1] = *(const bf16x8*)(vfb + dt * 32768 + (kt * 2 + 1) * 512);
        }

        floatx4 c[4][4] = {};
#pragma unroll
        for (int s = 0; s < 2; ++s)
#pragma unroll
            for (int kk = 0; kk < 4; ++kk)
#pragma unroll
                for (int qq = 0; qq < 4; ++qq)
                    c[kk][qq] = __builtin_amdgcn_mfma_f32_16x16x32_bf16(
                        ak[kk * 2 + s], bq[qq][s], c[kk][qq], 0, 0, 0);

        if (kt + 1 < 8) {
            const ushort* kp = kfb + (size_t)(kt + 1) * 4096;
#pragma unroll
            for (int kk = 0; kk < 4; ++kk) {
                ak[kk * 2 + 0] = *(const bf16x8*)(kp + kk * 1024);
                ak[kk * 2 + 1] = *(const bf16x8*)(kp + kk * 1024 + 512);
            }
        }

#pragma unroll
        for (int kk = 0; kk < 4; ++kk)
#pragma unroll
            for (int qq = 0; qq < 4; ++qq) {
                float e0 = EXP2(c[kk][qq][0]);
                float e1 = EXP2(c[kk][qq][1]);
                float e2 = EXP2(c[kk][qq][2]);
                float e3 = EXP2(c[kk][qq][3]);
                lsum[qq] += (e0 + e1) + (e2 + e3);
                uint2 u; u.x = pkbf(e0, e1); u.y = pkbf(e2, e3);
                *(uint2*)&sPw[(16 * qq + lr) * 72 + 16 * kk + 4 * lq] = u;
            }

#pragma unroll
        for (int s = 0; s < 2; ++s) {
            bf16x8 ap[4];
#pragma unroll
            for (int mi = 0; mi < 4; ++mi)
                ap[mi] = *(const bf16x8*)&sPw[(16 * mi + lr) * 72 + 32 * s + 8 * lq];
#pragma unroll
            for (int mi = 0; mi < 4; ++mi)
#pragma unroll
                for (int dt = 0; dt < 4; ++dt)
                    o[mi][dt] = __builtin_amdgcn_mfma_f32_16x16x32_bf16(
                        ap[mi], bv[dt * 2 + s], o[mi][dt], 0, 0, 0);
        }
    }

#pragma unroll
    for (int qq = 0; qq < 4; ++qq) {
        lsum[qq] += __shfl_xor(lsum[qq], 16);
        lsum[qq] += __shfl_xor(lsum[qq], 32);
    }

    float* Rw = sArena + w * 4352;
#pragma unroll
    for (int mi = 0; mi < 4; ++mi)
#pragma unroll
        for (int dt = 0; dt < 4; ++dt)
#pragma unroll
            for (int reg = 0; reg < 4; ++reg)
                Rw[(16 * mi + 4 * lq + reg) * 68 + 16 * dt + lr] = o[mi][dt][reg];
    if (lq == 0) {
#pragma unroll
        for (int qq = 0; qq < 4; ++qq) sL[w][16 * qq + lr] = lsum[qq];
    }
    __syncthreads();

    int qloc = 16 * w + (l >> 2);
    int c0 = (l & 3) * 16;
    float4 acc[4];
#pragma unroll
    for (int rg = 0; rg < 4; ++rg) {
        const float* R = sArena + rg * 4352 + qloc * 68 + c0;
#pragma unroll
        for (int c = 0; c < 4; ++c) {
            float4 v = *(const float4*)&R[4 * c];
            if (rg == 0) acc[c] = v;
            else { acc[c].x += v.x; acc[c].y += v.y; acc[c].z += v.z; acc[c].w += v.w; }
        }
    }
    float ltot = sL[0][qloc] + sL[1][qloc] + sL[2][qloc] + sL[3][qloc];
    float inv = 1.f / ltot;
    int m = (bh >> 3) * 2048 + qt * 64 + qloc;
    int kb = (bh & 7) * 64 + c0;
#pragma unroll
    for (int c = 0; c < 4; ++c) {
        uint2 u;
        u.x = pkbf(acc[c].x * inv, acc[c].y * inv);
        u.y = pkbf(acc[c].z * inv, acc[c].w * inv);
        *(uint2*)&attnf[frag_off(m, kb + 4 * c, 16)] = u;
    }
}

// ---------------------------------------------------------------------------
extern "C" void kernel_launch(void* const* d_in, const int* in_sizes, int n_in,
                              void* d_out, int out_size, void* d_ws, size_t ws_size,
                              hipStream_t stream) {
    const float* x   = (const float*)d_in[0];
    const float* g   = (const float*)d_in[1];
    const float* wq  = (const float*)d_in[2];
    const float* wkv = (const float*)d_in[3];
    const float* wo  = (const float*)d_in[4];
    float* out = (float*)d_out;

    char* ws = (char*)d_ws;
    float*  psum   = (float*)(ws + 0);          // 256K
    float*  psqr   = (float*)(ws + 262144);     // 256K
    ushort* xnf    = (ushort*)(ws + 524288);    // 8.39M frag-major K=1024
    ushort* wqkv_f = (ushort*)(ws + 8912896);   // 3.15M frag-major K=1024
    ushort* wo_f   = (ushort*)(ws + 12058624);  // 1.05M frag-major K=512
    ushort* qfb    = (ushort*)(ws + 13107200);  // 4.19M per-bh frag [row][d]
    ushort* kfb    = (ushort*)(ws + 17301504);  // 4.19M per-bh frag [row][d]
    ushort* vfb    = (ushort*)(ws + 21495808);  // 4.19M per-bh frag [d][key]
    ushort* attnf  = (ushort*)(ws + 25690112);  // 4.19M frag-major K=512

    setup_fused<<<2304, 256, 0, stream>>>(x, psum, psqr, wq, wkv, wo, wqkv_f, wo_f);
    finalize_norm<<<512, 256, 0, stream>>>(psum, psqr, x, g, xnf);
    gemm_qkv<<<768, 128, 0, stream>>>(xnf, wqkv_f, qfb, kfb, vfb);
    flash_attn<<<512, 256, 0, stream>>>(qfb, kfb, vfb, attnf);
    gemm_out<<<512, 128, 0, stream>>>(attnf, wo_f, out);
}

// Round 11
// 143.070 us; speedup vs baseline: 1.2639x; 1.0079x over previous
//
#include <hip/hip_runtime.h>
#include <hip/hip_bf16.h>
#include <stdint.h>

// B=2, N=2048, DIM=1024, HEADS=8, DIM_HEAD=64, INNER=512
// Round 11: ONE change vs round 10 — f2bf/pkbf switch from software RNE
// (~5 instr/value) to hardware bf16 cvt (gfx950 v_cvt_pk_bf16_f32, RNE):
// pkbf via __builtin_amdgcn_cvt_pk_bf16_f32 (guarded), f2bf via (__bf16)
// cast. Cuts flash softmax-pack VALU ~8x and gemm_qkv epilogue VALU.
// Rounding identical (RNE) -> absmax must stay exactly 1.831e-4.

#define B_ 2
#define N_ 2048
#define DIM_ 1024
#define DH_ 64
#define INNER_ 512
#define ROWS_ 4096
#define BHSTRIDE 131072    // 2048*64 elems per (b,h) for qf/kf/vf

// q scale 1/8 (=DH^-0.5) * log2(e), folded into wq cast; kernel uses exp2.
#define QSCALE 0.18033688011112042f

typedef __bf16 bf16x8 __attribute__((ext_vector_type(8)));
typedef float floatx4 __attribute__((ext_vector_type(4)));

#if __has_builtin(__builtin_amdgcn_exp2f)
#define EXP2(x) __builtin_amdgcn_exp2f(x)
#else
#define EXP2(x) exp2f(x)
#endif

// HW bf16 conversion (RNE). Scalar: native cast (gfx950 lowers to
// v_cvt_pk_bf16_f32). Packed: builtin when available, else two casts.
__device__ __forceinline__ ushort f2bf(float f) {
    union { __bf16 h; ushort u; } v;
    v.h = (__bf16)f;
    return v.u;
}
#if __has_builtin(__builtin_amdgcn_cvt_pk_bf16_f32)
__device__ __forceinline__ uint32_t pkbf(float a, float b) {
    auto h = __builtin_amdgcn_cvt_pk_bf16_f32(a, b);
    union { decltype(h) h; uint32_t u; } v;
    v.h = h;
    return v.u;
}
#else
__device__ __forceinline__ uint32_t pkbf(float a, float b) {
    return (uint32_t)f2bf(a) | ((uint32_t)f2bf(b) << 16);
}
#endif

// frag-major element offset: lane l of a wave holds M=16*T+(l&15),
// k = 32*kc + 8*(l>>4) + j  (j=0..7). nkc = K/32.
__device__ __forceinline__ size_t frag_off(int m, int k, int nkc) {
    return ((size_t)((m >> 4) * nkc + (k >> 5)) * 64 +
            (size_t)((m & 15) | (((k >> 3) & 3) << 4))) * 8 + (k & 7);
}

// ---------------------------------------------------------------------------
// K1: fused setup. blocks 0..255: partial column stats (seq axis).
// blocks 256..2303: weight cast into frag-major layouts.
__global__ __launch_bounds__(256) void setup_fused(
    const float* __restrict__ x, float* __restrict__ ps, float* __restrict__ pq,
    const float* __restrict__ wq, const float* __restrict__ wkv,
    const float* __restrict__ wo, ushort* __restrict__ wqkv_f,
    ushort* __restrict__ wo_f) {
    __shared__ float tile[32][33];
    int bid = blockIdx.x;
    if (bid < 256) {
        int gd = (bid & 7) * 256 + threadIdx.x;   // b*1024 + c
        int ch = bid >> 3;                        // 0..31
        int b = gd >> 10;
        const float* p = x + (size_t)(b * N_ + ch * 64) * DIM_ + (gd & 1023);
        float s = 0.f, q = 0.f;
#pragma unroll 4
        for (int n = 0; n < 64; ++n) { float v = p[(size_t)n * DIM_]; s += v; q += v * v; }
        ps[ch * 2048 + gd] = s;
        pq[ch * 2048 + gd] = q;
        return;
    }
    int t = bid - 256;
    const float* src; ushort* dst; int C, K, k0, ncol0, nglob0; float scale;
    if (t < 512) {
        int kt = t >> 4, nt = t & 15;
        src = wq; dst = wqkv_f; C = 512; K = 1024; scale = QSCALE;
        k0 = kt * 32; ncol0 = nt * 32; nglob0 = ncol0;
    } else if (t < 1536) {
        int u = t - 512; int kt = u >> 5, nt = u & 31;
        src = wkv; dst = wqkv_f; C = 1024; K = 1024; scale = 1.f;
        k0 = kt * 32; ncol0 = nt * 32; nglob0 = 512 + ncol0;
    } else {
        int u = t - 1536; int kt = u >> 5, nt = u & 31;
        src = wo; dst = wo_f; C = 1024; K = 512; scale = 1.f;
        k0 = kt * 32; ncol0 = nt * 32; nglob0 = ncol0;
    }
    int ti = threadIdx.x >> 5, tj = threadIdx.x & 31;
#pragma unroll
    for (int p = 0; p < 4; ++p)
        tile[ti + 8 * p][tj] = src[(size_t)(k0 + ti + 8 * p) * C + ncol0 + tj] * scale;
    __syncthreads();
    if (threadIdx.x < 128) {
        int nl = threadIdx.x & 31, kc8 = threadIdx.x >> 5;
        union { ushort us[8]; uint4 v; } u;
#pragma unroll
        for (int ii = 0; ii < 8; ++ii) u.us[ii] = f2bf(tile[kc8 * 8 + ii][nl]);
        *(uint4*)&dst[frag_off(nglob0 + nl, k0 + kc8 * 8, K >> 5)] = u.v;
    }
}

// ---------------------------------------------------------------------------
// K2: fused finalize + normalize + cast to frag-major xn. grid 512, block 256.
__global__ __launch_bounds__(256) void finalize_norm(
    const float* __restrict__ ps, const float* __restrict__ pq,
    const float* __restrict__ x, const float* __restrict__ g,
    ushort* __restrict__ xnf) {
    __shared__ float s4[4][64], q4[4][64], aa[64], bb[64];
    int t = threadIdx.x;
    int b = blockIdx.x >> 8, slab = (blockIdx.x >> 4) & 15, nch = blockIdx.x & 15;
    int c0 = slab * 64;
    {
        int c = t & 63, grp = t >> 6;
        float s = 0.f, q = 0.f;
#pragma unroll
        for (int ch = 0; ch < 8; ++ch) {
            int o = (grp * 8 + ch) * 2048 + b * 1024 + c0 + c;
            s += ps[o]; q += pq[o];
        }
        s4[grp][c] = s; q4[grp][c] = q;
    }
    __syncthreads();
    if (t < 64) {
        float s = s4[0][t] + s4[1][t] + s4[2][t] + s4[3][t];
        float q = q4[0][t] + q4[1][t] + q4[2][t] + q4[3][t];
        float mean = s * (1.f / N_);
        float var = q * (1.f / N_) - mean * mean;
        float rstd = rsqrtf(var + 1e-5f);
        float a = rstd * g[c0 + t];
        aa[t] = a; bb[t] = -mean * a;
    }
    __syncthreads();
    int c4 = (t & 15) * 4, ro = t >> 4;
#pragma unroll
    for (int it = 0; it < 8; ++it) {
        int r = nch * 128 + it * 16 + ro;
        int m = b * 2048 + r;
        float4 xv = *(const float4*)&x[(size_t)m * DIM_ + c0 + c4];
        float v0 = xv.x * aa[c4 + 0] + bb[c4 + 0];
        float v1 = xv.y * aa[c4 + 1] + bb[c4 + 1];
        float v2 = xv.z * aa[c4 + 2] + bb[c4 + 2];
        float v3 = xv.w * aa[c4 + 3] + bb[c4 + 3];
        uint2 u; u.x = pkbf(v0, v1); u.y = pkbf(v2, v3);
        *(uint2*)&xnf[frag_off(m, c0 + c4, 32)] = u;
    }
}

// ---------------------------------------------------------------------------
// LDS-free GEMM core: ROLLED 3-stage register pipeline (round-10 win).
template <int NKC>
__device__ __forceinline__ void gemm_core(
    const ushort* __restrict__ pA, const ushort* __restrict__ pB,
    floatx4 (&acc)[4][4]) {
    constexpr int TS = NKC * 512;
    bf16x8 a0[4], b0[4], a1[4], b1[4], a2[4], b2[4];
    auto ld = [&](bf16x8 (&a)[4], bf16x8 (&b)[4], int kc) {
#pragma unroll
        for (int i = 0; i < 4; ++i) {
            a[i] = *(const bf16x8*)(pA + (size_t)i * TS + (size_t)kc * 512);
            b[i] = *(const bf16x8*)(pB + (size_t)i * TS + (size_t)kc * 512);
        }
    };
    auto mm = [&](bf16x8 (&a)[4], bf16x8 (&b)[4]) {
#pragma unroll
        for (int mi = 0; mi < 4; ++mi)
#pragma unroll
            for (int ni = 0; ni < 4; ++ni)
                acc[mi][ni] = __builtin_amdgcn_mfma_f32_16x16x32_bf16(
                    a[mi], b[ni], acc[mi][ni], 0, 0, 0);
    };
    ld(a0, b0, 0);
    ld(a1, b1, 1);
    int kc = 0;
    for (; kc + 3 <= NKC; kc += 3) {
        ld(a2, b2, kc + 2);
        mm(a0, b0);
        if (kc + 3 < NKC) ld(a0, b0, kc + 3);
        mm(a1, b1);
        if (kc + 4 < NKC) ld(a1, b1, kc + 4);
        mm(a2, b2);
    }
    if (NKC % 3 >= 1) mm(a0, b0);     // stage kc
    if (NKC % 3 == 2) mm(a1, b1);     // stage kc+1
}

// K3: qkv GEMM. 1D grid 768, block 128. XCD swizzle: XCD j owns bx slab
// j*8..j*8+7 (A rows L2-resident per XCD).
__global__ __launch_bounds__(128) void gemm_qkv(
    const ushort* __restrict__ xnf, const ushort* __restrict__ wf,
    ushort* __restrict__ qf, ushort* __restrict__ kf, ushort* __restrict__ vf) {
    int tx = threadIdx.x, w = tx >> 6, l = tx & 63;
    int lr = l & 15, lq = l >> 4;
    int bid = blockIdx.x;
    int xcd = bid & 7, t = bid >> 3;          // t: 0..95
    int bx = xcd * 8 + (t & 7);               // 0..63
    int by = t >> 3;                          // 0..11
    const ushort* pA = xnf + (size_t)(bx * 4) * 32 * 512 + l * 8;
    const ushort* pB = wf + (size_t)(by * 8 + w * 4) * 32 * 512 + l * 8;
    floatx4 acc[4][4] = {};
    gemm_core<32>(pA, pB, acc);
    int col0 = by * 128 + w * 64;
    int bb2 = (bx * 64) >> 11;
    if (by < 8) {
        ushort* qkbase = (by < 4) ? qf : kf;
#pragma unroll
        for (int ni = 0; ni < 4; ++ni) {
            int col = col0 + 16 * ni + lr;
            int hh = (col >> 6) & 7, d = col & 63;
            ushort* base = qkbase + (size_t)(bb2 * 8 + hh) * BHSTRIDE
                           + (d >> 5) * 512 + ((d >> 3) & 3) * 128 + (d & 7)
                           + (4 * lq) * 8;
#pragma unroll
            for (int mi = 0; mi < 4; ++mi) {
                size_t o2 = (size_t)((bx * 4 + mi) & 127) * 1024;
#pragma unroll
                for (int reg = 0; reg < 4; ++reg)
                    base[o2 + reg * 8] = f2bf(acc[mi][ni][reg]);
            }
        }
    } else {
#pragma unroll
        for (int ni = 0; ni < 4; ++ni) {
            int cv = col0 - 1024 + 16 * ni + lr;
            int hh = cv >> 6, d = cv & 63;
            ushort* base = vf + (size_t)(bb2 * 8 + hh) * BHSTRIDE
                           + (d >> 4) * 32768 + (d & 15) * 8;
#pragma unroll
            for (int mi = 0; mi < 4; ++mi) {
                int nn = (bx * 64 + 16 * mi + 4 * lq) & 2047;
                uint2 u;
                u.x = pkbf(acc[mi][ni][0], acc[mi][ni][1]);
                u.y = pkbf(acc[mi][ni][2], acc[mi][ni][3]);
                *(uint2*)&base[(nn >> 5) * 512 + ((nn >> 3) & 3) * 128 + (nn & 7)] = u;
            }
        }
    }
}

// K5: out GEMM. 1D grid 512, block 128, XCD swizzle as above.
__global__ __launch_bounds__(128) void gemm_out(
    const ushort* __restrict__ af, const ushort* __restrict__ wf,
    float* __restrict__ out) {
    int tx = threadIdx.x, w = tx >> 6, l = tx & 63;
    int lr = l & 15, lq = l >> 4;
    int bid = blockIdx.x;
    int xcd = bid & 7, t = bid >> 3;          // t: 0..63
    int bx = xcd * 8 + (t & 7);               // 0..63
    int by = t >> 3;                          // 0..7
    const ushort* pA = af + (size_t)(bx * 4) * 16 * 512 + l * 8;
    const ushort* pB = wf + (size_t)(by * 8 + w * 4) * 16 * 512 + l * 8;
    floatx4 acc[4][4] = {};
    gemm_core<16>(pA, pB, acc);
    int col0 = by * 128 + w * 64;
#pragma unroll
    for (int mi = 0; mi < 4; ++mi)
#pragma unroll
        for (int ni = 0; ni < 4; ++ni) {
            int col = col0 + 16 * ni + lr;
#pragma unroll
            for (int reg = 0; reg < 4; ++reg) {
                int row = bx * 64 + 16 * mi + 4 * lq + reg;
                out[(size_t)row * 1024 + col] = acc[mi][ni][reg];
            }
        }
}

// ---------------------------------------------------------------------------
// K4: flash with in-block split-merge (structure identical to round 9/10).
__global__ __launch_bounds__(256, 2) void flash_attn(
    const ushort* __restrict__ qf, const ushort* __restrict__ kf,
    const ushort* __restrict__ vf, ushort* __restrict__ attnf) {
    __shared__ __align__(16) float sArena[4 * 4352];  // P (loop) / O 64x68 (merge)
    __shared__ float sL[4][64];

    const int tx = threadIdx.x;
    const int w = tx >> 6, l = tx & 63;
    const int lr = l & 15, lq = l >> 4;
    const int bid = blockIdx.x;
    const int bh = (bid & 7) * 2 + ((bid >> 3) & 1);
    const int qt = bid >> 4;                 // 0..31 (tile of 64 q rows)

    const ushort* qfb = qf + (size_t)bh * BHSTRIDE + (size_t)(qt * 4) * 1024 + l * 8;
    const ushort* kfb = kf + (size_t)bh * BHSTRIDE + (size_t)w * 32768 + l * 8;
    const ushort* vfb = vf + (size_t)bh * BHSTRIDE + (size_t)w * 8192 + l * 8;
    ushort* sPw = (ushort*)(sArena + w * 4352);

    bf16x8 bq[4][2];
#pragma unroll
    for (int qq = 0; qq < 4; ++qq)
#pragma unroll
        for (int s = 0; s < 2; ++s)
            bq[qq][s] = *(const bf16x8*)(qfb + qq * 1024 + s * 512);

    floatx4 o[4][4] = {};
    float lsum[4] = {0.f, 0.f, 0.f, 0.f};

    bf16x8 ak[8], bv[8];
#pragma unroll
    for (int kk = 0; kk < 4; ++kk) {
        ak[kk * 2 + 0] = *(const bf16x8*)(kfb + kk * 1024);
        ak[kk * 2 + 1] = *(const bf16x8*)(kfb + kk * 1024 + 512);
    }

    for (int kt = 0; kt < 8; ++kt) {
#pragma unroll
        for (int dt = 0; dt < 4; ++dt) {
            bv[dt * 2 + 0] = *(const bf16x8*)(vfb + dt * 32768 + (kt * 2 + 0) * 512);
            bv[dt * 2 + 1] = *(const bf16x8*)(vfb + dt * 32768 + (kt * 2 + 1) * 512);
        }

        floatx4 c[4][4] = {};
#pragma unroll
        for (int s = 0; s < 2; ++s)
#pragma unroll
            for (int kk = 0; kk < 4; ++kk)
#pragma unroll
                for (int qq = 0; qq < 4; ++qq)
                    c[kk][qq] = __builtin_amdgcn_mfma_f32_16x16x32_bf16(
                        ak[kk * 2 + s], bq[qq][s], c[kk][qq], 0, 0, 0);

        if (kt + 1 < 8) {
            const ushort* kp = kfb + (size_t)(kt + 1) * 4096;
#pragma unroll
            for (int kk = 0; kk < 4; ++kk) {
                ak[kk * 2 + 0] = *(const bf16x8*)(kp + kk * 1024);
                ak[kk * 2 + 1] = *(const bf16x8*)(kp + kk * 1024 + 512);
            }
        }

#pragma unroll
        for (int kk = 0; kk < 4; ++kk)
#pragma unroll
            for (int qq = 0; qq < 4; ++qq) {
                float e0 = EXP2(c[kk][qq][0]);
                float e1 = EXP2(c[kk][qq][1]);
                float e2 = EXP2(c[kk][qq][2]);
                float e3 = EXP2(c[kk][qq][3]);
                lsum[qq] += (e0 + e1) + (e2 + e3);
                uint2 u; u.x = pkbf(e0, e1); u.y = pkbf(e2, e3);
                *(uint2*)&sPw[(16 * qq + lr) * 72 + 16 * kk + 4 * lq] = u;
            }

#pragma unroll
        for (int s = 0; s < 2; ++s) {
            bf16x8 ap[4];
#pragma unroll
            for (int mi = 0; mi < 4; ++mi)
                ap[mi] = *(const bf16x8*)&sPw[(16 * mi + lr) * 72 + 32 * s + 8 * lq];
#pragma unroll
            for (int mi = 0; mi < 4; ++mi)
#pragma unroll
                for (int dt = 0; dt < 4; ++dt)
                    o[mi][dt] = __builtin_amdgcn_mfma_f32_16x16x32_bf16(
                        ap[mi], bv[dt * 2 + s], o[mi][dt], 0, 0, 0);
        }
    }

#pragma unroll
    for (int qq = 0; qq < 4; ++qq) {
        lsum[qq] += __shfl_xor(lsum[qq], 16);
        lsum[qq] += __shfl_xor(lsum[qq], 32);
    }

    float* Rw = sArena + w * 4352;
#pragma unroll
    for (int mi = 0; mi < 4; ++mi)
#pragma unroll
        for (int dt = 0; dt < 4; ++dt)
#pragma unroll
            for (int reg = 0; reg < 4; ++reg)
                Rw[(16 * mi + 4 * lq + reg) * 68 + 16 * dt + lr] = o[mi][dt][reg];
    if (lq == 0) {
#pragma unroll
        for (int qq = 0; qq < 4; ++qq) sL[w][16 * qq + lr] = lsum[qq];
    }
    __syncthreads();

    int qloc = 16 * w + (l >> 2);
    int c0 = (l & 3) * 16;
    float4 acc[4];
#pragma unroll
    for (int rg = 0; rg < 4; ++rg) {
        const float* R = sArena + rg * 4352 + qloc * 68 + c0;
#pragma unroll
        for (int c = 0; c < 4; ++c) {
            float4 v = *(const float4*)&R[4 * c];
            if (rg == 0) acc[c] = v;
            else { acc[c].x += v.x; acc[c].y += v.y; acc[c].z += v.z; acc[c].w += v.w; }
        }
    }
    float ltot = sL[0][qloc] + sL[1][qloc] + sL[2][qloc] + sL[3][qloc];
    float inv = 1.f / ltot;
    int m = (bh >> 3) * 2048 + qt * 64 + qloc;
    int kb = (bh & 7) * 64 + c0;
#pragma unroll
    for (int c = 0; c < 4; ++c) {
        uint2 u;
        u.x = pkbf(acc[c].x * inv, acc[c].y * inv);
        u.y = pkbf(acc[c].z * inv, acc[c].w * inv);
        *(uint2*)&attnf[frag_off(m, kb + 4 * c, 16)] = u;
    }
}

// ---------------------------------------------------------------------------
extern "C" void kernel_launch(void* const* d_in, const int* in_sizes, int n_in,
                              void* d_out, int out_size, void* d_ws, size_t ws_size,
                              hipStream_t stream) {
    const float* x   = (const float*)d_in[0];
    const float* g   = (const float*)d_in[1];
    const float* wq  = (const float*)d_in[2];
    const float* wkv = (const float*)d_in[3];
    const float* wo  = (const float*)d_in[4];
    float* out = (float*)d_out;

    char* ws = (char*)d_ws;
    float*  psum   = (float*)(ws + 0);          // 256K
    float*  psqr   = (float*)(ws + 262144);     // 256K
    ushort* xnf    = (ushort*)(ws + 524288);    // 8.39M frag-major K=1024
    ushort* wqkv_f = (ushort*)(ws + 8912896);   // 3.15M frag-major K=1024
    ushort* wo_f   = (ushort*)(ws + 12058624);  // 1.05M frag-major K=512
    ushort* qfb    = (ushort*)(ws + 13107200);  // 4.19M per-bh frag [row][d]
    ushort* kfb    = (ushort*)(ws + 17301504);  // 4.19M per-bh frag [row][d]
    ushort* vfb    = (ushort*)(ws + 21495808);  // 4.19M per-bh frag [d][key]
    ushort* attnf  = (ushort*)(ws + 25690112);  // 4.19M frag-major K=512

    setup_fused<<<2304, 256, 0, stream>>>(x, psum, psqr, wq, wkv, wo, wqkv_f, wo_f);
    finalize_norm<<<512, 256, 0, stream>>>(psum, psqr, x, g, xnf);
    gemm_qkv<<<768, 128, 0, stream>>>(xnf, wqkv_f, qfb, kfb, vfb);
    flash_attn<<<512, 256, 0, stream>>>(qfb, kfb, vfb, attnf);
    gemm_out<<<512, 128, 0, stream>>>(attnf, wo_f, out);
}